// Round 22
// baseline (152.302 us; speedup 1.0000x reference)
//
#include <hip/hip_runtime.h>

#define V      6890
#define NJ     24
#define NB     10
#define NP     207
#define NK     19
#define NBATCH 2048
#define KP     224      // padded K: 10 beta + 207 lrotmin + 1 const + 6 zero
#define KC     217      // constant-1 column (-> v_template)
#define VC     (V*3)    // 20670
#define VCP    20736    // padded VC
#define BN     64       // n-tile
#define BV     64       // v-tile per block
#define VST4   260      // vhsm row stride in shorts (520 B: 8B-aligned, jg-groups 8 banks apart)
#define VSEG   1723     // ceil(V/4) for V-splits (k_prep JB dots)
#define JSP    18       // joints GEMM K-split
#define JCH    9        // chunks per slice; chunk = 4 k-steps = 128 floats
#define JBN    64       // joints n-tile (R22: doubled to halve JbigT re-read)
#define BWSZ   1536     // per-wave per-buffer B slice, shorts (48 rows x 32)

using bh8   = __attribute__((ext_vector_type(8))) short;          // 8 x bf16
using u16x4 = __attribute__((ext_vector_type(4))) unsigned short;
using u16x8 = __attribute__((ext_vector_type(8))) unsigned short;
using f32x4 = __attribute__((ext_vector_type(4))) float;

__constant__ int PAR[NJ] = {-1,0,0,0,1,2,3,4,5,6,7,8,9,9,9,12,13,14,16,17,18,19,20,21};

__device__ __forceinline__ unsigned short f2bf(float f) {
    unsigned int u = __float_as_uint(f);
    u += 0x7FFFu + ((u >> 16) & 1u);   // RNE; no NaNs in this data
    return (unsigned short)(u >> 16);
}
__device__ __forceinline__ float bf2f(unsigned short h) {
    return __uint_as_float((unsigned int)h << 16);
}

// ---------------- K_prep: fused [JB dots | Bmat 8-wide | JbigT 8-wide | Wb bf16] ----------------
__global__ __launch_bounds__(256) void k_prep(const float* __restrict__ Jreg,
                                              const float* __restrict__ vtmpl,
                                              const float* __restrict__ sdirs,
                                              const float* __restrict__ pdirs,
                                              const float* __restrict__ jreg,
                                              const float* __restrict__ weights,
                                              float* __restrict__ JB,
                                              unsigned short* __restrict__ Bmat,
                                              unsigned short* __restrict__ JbigT,
                                              unsigned short* __restrict__ Wb) {
    int blk = blockIdx.x, tid = threadIdx.x;
    if (blk < 792) {                       // JB partial dots, 4-way V-split, atomic accumulate
        int vs = blk & 3, og = blk >> 2;
        int o = og*4 + (tid >> 6);         // o in [0,792) = 24*33
        int lane = tid & 63;
        int j = o/33, t = o%33, c = t/11, m = t%11;
        int lo = vs*VSEG + lane, hi = min(V, vs*VSEG + VSEG);
        const float* jr = Jreg + j*V;
        float s = 0.f;
        if (m == 0) { for (int v = lo; v < hi; v += 64) s += jr[v] * vtmpl[v*3 + c]; }
        else        { for (int v = lo; v < hi; v += 64) s += jr[v] * sdirs[(v*3 + c)*NB + (m-1)]; }
        #pragma unroll
        for (int d = 1; d < 64; d <<= 1) s += __shfl_xor(s, d);
        if (lane == 0) atomicAdd(&JB[(j*3 + c)*11 + m], s);
    } else if (blk < 792 + 2268) {         // Bmat: thread handles (vc, 8 consecutive k)
        int gid = (blk - 792)*256 + tid;   // [0, VCP*28)
        int vc = gid / 28, q = gid - vc*28;
        int k0 = q*8;
        unsigned short out[8];
        if (vc >= VC) {
            #pragma unroll
            for (int j = 0; j < 8; ++j) out[j] = 0;
        } else if (q >= 2 && q <= 26) {    // pure pdirs span (k in [16,215])
            const float* p = pdirs + (size_t)vc*NP + (k0 - NB);
            #pragma unroll
            for (int j = 0; j < 8; ++j) out[j] = f2bf(p[j]);
        } else {
            #pragma unroll
            for (int j = 0; j < 8; ++j) {
                int k = k0 + j;
                float val;
                if (k < NB)       val = sdirs[vc*NB + k];
                else if (k < KC)  val = pdirs[(size_t)vc*NP + (k - NB)];
                else if (k == KC) val = vtmpl[vc];
                else              val = 0.f;
                out[j] = f2bf(val);
            }
        }
        *(u16x8*)&Bmat[((size_t)(k0 >> 5)*VCP + vc)*32 + (k0 & 31)] = *(u16x8*)out;
    } else if (blk < 792 + 2268 + 648) {   // JbigT: thread handles (kc, 8 consecutive vc)
        int gid = (blk - 792 - 2268)*256 + tid;   // [0, 64*VCP/8)
        int kc = gid / (VCP/8), u = gid - kc*(VCP/8);
        int vc0 = u*8;
        unsigned short out[8];
        #pragma unroll
        for (int j = 0; j < 8; ++j) out[j] = 0;
        if (kc < NK*3) {
            #pragma unroll
            for (int j = 0; j < 8; ++j) {
                int vc = vc0 + j;
                if (vc < VC && (vc % 3) == (kc % 3))
                    out[j] = f2bf(jreg[(vc/3)*NK + (kc/3)]);
            }
        }
        *(u16x8*)&JbigT[((size_t)(vc0 >> 5)*64 + kc)*32 + (vc0 & 31)] = *(u16x8*)out;
    } else {                               // Wb[v][32] bf16: weights zero-padded to 32 cols
        int gid = (blk - 792 - 2268 - 648)*256 + tid;   // [0, V*4)
        if (gid < V*4) {
            int v = gid >> 2, q = gid & 3;
            unsigned short out[8];
            #pragma unroll
            for (int j = 0; j < 8; ++j) {
                int jj = q*8 + j;
                out[j] = (jj < NJ) ? f2bf(weights[(size_t)v*NJ + jj]) : (unsigned short)0;
            }
            *(u16x8*)&Wb[(size_t)v*32 + q*8] = *(u16x8*)out;
        }
    }
}

// ---------------- K_pern: one WAVE per n (64-thread block; barriers ~free) ----------------
__global__ __launch_bounds__(64) void k_pern(const float* __restrict__ beta,
                                             const float* __restrict__ theta,
                                             const float* __restrict__ trans,
                                             const float* __restrict__ JB,
                                             unsigned short* __restrict__ Arow,
                                             unsigned short* __restrict__ Gt) {
    int n = blockIdx.x, tid = threadIdx.x;
    __shared__ float Rsm[NJ][9];
    __shared__ float Jsm[NJ][3];
    __shared__ float Gsm[NJ][12];   // 3x4, e = a*4+b

    if (tid < NJ) {                 // lanes 0-23: rodrigues
        const float* th = theta + (n*NJ + tid)*3;
        float x = th[0], y = th[1], z = th[2];
        float nrm = sqrtf(x*x + y*y + z*z);
        float t = fmaxf(nrm, 1.1754944e-38f);
        float inv = 1.0f / t;
        float rx = x*inv, ry = y*inv, rz = z*inv;
        float c = cosf(t), s = sinf(t), oc = 1.0f - c;
        Rsm[tid][0] = c + oc*rx*rx;      Rsm[tid][1] = oc*rx*ry - s*rz;  Rsm[tid][2] = oc*rx*rz + s*ry;
        Rsm[tid][3] = oc*ry*rx + s*rz;   Rsm[tid][4] = c + oc*ry*ry;     Rsm[tid][5] = oc*ry*rz - s*rx;
        Rsm[tid][6] = oc*rz*rx - s*ry;   Rsm[tid][7] = oc*rz*ry + s*rx;  Rsm[tid][8] = c + oc*rz*rz;
    } else if (tid < 2*NJ) {        // lanes 24-47: J rows (3 dots of 11 each)
        int j = tid - NJ;
        #pragma unroll
        for (int c = 0; c < 3; ++c) {
            float s = JB[(j*3+c)*11 + 0];
            #pragma unroll
            for (int b = 0; b < NB; ++b) s += JB[(j*3+c)*11 + 1 + b] * beta[n*NB + b];
            Jsm[j][c] = s;
        }
    }
    __syncthreads();

    if (tid < 12) {
        int a = tid >> 2, b = tid & 3;
        Gsm[0][a*4+b] = (b < 3) ? Rsm[0][a*3+b] : Jsm[0][a];
    }
    __syncthreads();
    for (int i = 1; i < NJ; ++i) {
        if (tid < 12) {
            int a = tid >> 2, b = tid & 3;
            int p = PAR[i];
            float acc = (b == 3) ? Gsm[p][a*4+3] : 0.0f;
            #pragma unroll
            for (int k = 0; k < 3; ++k) {
                float aval = (b < 3) ? Rsm[i][k*3+b] : (Jsm[i][k] - Jsm[p][k]);
                acc += Gsm[p][a*4+k] * aval;
            }
            Gsm[i][a*4+b] = acc;
        }
        __syncthreads();
    }
    if (tid < NJ) {   // t' = t - R.J + trans (trans folds: sum_j w = 1)
        int j = tid;
        #pragma unroll
        for (int a = 0; a < 3; ++a) {
            float t3 = Gsm[j][a*4+3]
                     - (Gsm[j][a*4+0]*Jsm[j][0] + Gsm[j][a*4+1]*Jsm[j][1] + Gsm[j][a*4+2]*Jsm[j][2])
                     + trans[n*3 + a];
            Gsm[j][a*4+3] = t3;
        }
    }
    __syncthreads();
    // Gt[n][e=0..15][j=0..31] bf16 zero-padded
    unsigned short* gt = Gt + n*512;
    for (int idx = tid; idx < 512; idx += 64) {
        int e = idx >> 5, j = idx & 31;
        float val = (e < 12 && j < NJ) ? Gsm[j][e] : 0.0f;
        gt[idx] = f2bf(val);
    }
    // A-row, K-tiled layout [k/32][n][32]
    for (int k = tid; k < KP; k += 64) {
        float val;
        if (k < NB) val = beta[n*NB + k];
        else if (k < KC) {
            int p = k - NB; int jj = p/9 + 1; int rr = p%9;
            val = Rsm[jj][rr] - ((rr==0 || rr==4 || rr==8) ? 1.0f : 0.0f);
        } else if (k == KC) val = 1.0f;
        else val = 0.0f;
        Arow[((size_t)(k >> 5)*NBATCH + n)*32 + (k & 31)] = f2bf(val);
    }
}

// ---------------- K_main: R18/R20/R21 structure (best known) ----------------
__global__ __launch_bounds__(512) void k_main(const unsigned short* __restrict__ Arow,
                                              const unsigned short* __restrict__ Bmat,
                                              const unsigned short* __restrict__ Gt,
                                              const unsigned short* __restrict__ Wb,
                                              float* __restrict__ verts) {
    __shared__ __attribute__((aligned(16))) char smem[49152];
    unsigned short* Bw   = (unsigned short*)smem;   // [8 waves][2 bufs][BWSZ]
    unsigned short* vhsm = (unsigned short*)smem;   // overlaid [BN*VST4] (33280 B)

    int tid = threadIdx.x;
    int wv = tid >> 6, lane = tid & 63;
    int l15 = lane & 15, jg = lane >> 4;
    int wn = wv >> 2, wc = wv & 3;             // n-half (0/1), vc-quarter (0..3)
    int nb = blockIdx.x, vb = blockIdx.y;      // x-fastest: 32 consecutive blocks share B slice
    int n0 = nb * BN, v0 = vb * BV, vc0 = v0 * 3;

    // per-lane spill column mapping (vc -> padded-4 col)
    int c4[3];
    #pragma unroll
    for (int ct = 0; ct < 3; ++ct) {
        int vcw = wc*48 + ct*16 + l15;          // [0,192)
        c4[ct] = (vcw/3)*4 + vcw%3;
    }
    int tri = (((lane % 3)*16) + lane/3) * 4;   // bpermute byte index for output transpose

    unsigned short* bw0 = &Bw[wv*2*BWSZ];
    unsigned short* bw1 = bw0 + BWSZ;
    const unsigned short* bsrc0 = Bmat + ((size_t)(vc0 + wc*48))*32;
    auto stageB = [&](unsigned short* dst, int ks) {   // 3 x 1KB async, zero VGPR payload
        const unsigned short* s = bsrc0 + (size_t)ks*VCP*32;
        #pragma unroll
        for (int i = 0; i < 3; ++i) {
            __builtin_amdgcn_global_load_lds(
                (const __attribute__((address_space(1))) void*)(s + i*512 + (size_t)lane*8),
                (__attribute__((address_space(3))) void*)(dst + i*512),
                16, 0, 0);
        }
    };

    const unsigned short* abase = Arow + ((size_t)(n0 + wn*32) + l15)*32 + jg*8;

    // ---- prologue: issue groups {S(0),A(0)} and {S(1),A(1)}, order pinned ----
    stageB(bw0, 0);
    bh8 aA0 = *(const bh8*)(abase);
    bh8 aA1 = *(const bh8*)(abase + 16*32);
    __builtin_amdgcn_sched_barrier(0);
    stageB(bw1, 1);
    bh8 aB0 = *(const bh8*)(abase + (size_t)NBATCH*32);
    bh8 aB1 = *(const bh8*)(abase + (size_t)NBATCH*32 + 16*32);
    __builtin_amdgcn_sched_barrier(0);

    // ---- GEMM1: counted-vmcnt depth-2 pipeline, NO block barriers ----
    f32x4 acc[2][3] = {};
    #pragma unroll
    for (int ks = 0; ks < 7; ++ks) {
        // queue (oldest first): group(ks)=5, group(ks+1)=5  -> wait group(ks) only
        if (ks < 6) asm volatile("s_waitcnt vmcnt(5)" ::: "memory");
        else        asm volatile("s_waitcnt vmcnt(0)" ::: "memory");
        __builtin_amdgcn_sched_barrier(0);
        unsigned short* bcur = (ks & 1) ? bw1 : bw0;
        bh8 b0 = *(const bh8*)(bcur + ( 0 + l15)*32 + jg*8);
        bh8 b1 = *(const bh8*)(bcur + (16 + l15)*32 + jg*8);
        bh8 b2 = *(const bh8*)(bcur + (32 + l15)*32 + jg*8);
        asm volatile("s_waitcnt lgkmcnt(0)" ::: "memory");   // b in regs -> bcur reusable
        __builtin_amdgcn_sched_barrier(0);
        bh8 a0 = (ks & 1) ? aB0 : aA0;
        bh8 a1 = (ks & 1) ? aB1 : aA1;
        if (ks + 2 <= 6) {        // issue group(ks+2) into bcur (now free)
            stageB(bcur, ks + 2);
            if (ks & 1) {
                aB0 = *(const bh8*)(abase + (size_t)(ks+2)*NBATCH*32);
                aB1 = *(const bh8*)(abase + (size_t)(ks+2)*NBATCH*32 + 16*32);
            } else {
                aA0 = *(const bh8*)(abase + (size_t)(ks+2)*NBATCH*32);
                aA1 = *(const bh8*)(abase + (size_t)(ks+2)*NBATCH*32 + 16*32);
            }
            __builtin_amdgcn_sched_barrier(0);
        }
        __builtin_amdgcn_s_setprio(1);
        acc[0][0] = __builtin_amdgcn_mfma_f32_16x16x32_bf16(a0, b0, acc[0][0], 0, 0, 0);
        acc[0][1] = __builtin_amdgcn_mfma_f32_16x16x32_bf16(a0, b1, acc[0][1], 0, 0, 0);
        acc[0][2] = __builtin_amdgcn_mfma_f32_16x16x32_bf16(a0, b2, acc[0][2], 0, 0, 0);
        acc[1][0] = __builtin_amdgcn_mfma_f32_16x16x32_bf16(a1, b0, acc[1][0], 0, 0, 0);
        acc[1][1] = __builtin_amdgcn_mfma_f32_16x16x32_bf16(a1, b1, acc[1][1], 0, 0, 0);
        acc[1][2] = __builtin_amdgcn_mfma_f32_16x16x32_bf16(a1, b2, acc[1][2], 0, 0, 0);
        __builtin_amdgcn_s_setprio(0);
    }

    __syncthreads();   // all waves done with Bw -> region becomes vhsm

    // spill (bf16, padded-4): row = wn*32 + mt*16 + jg*4 + r, col = c4[ct]
    #pragma unroll
    for (int mt = 0; mt < 2; ++mt)
        #pragma unroll
        for (int ct = 0; ct < 3; ++ct)
            #pragma unroll
            for (int r = 0; r < 4; ++r)
                vhsm[(wn*32 + mt*16 + jg*4 + r)*VST4 + c4[ct]] = f2bf(acc[mt][ct][r]);
    __syncthreads();

    // W fragments: single 16B loads from pre-converted Wb (jg=3 rows read zeros)
    bh8 wfrag[4];
    #pragma unroll
    for (int mt = 0; mt < 4; ++mt)
        wfrag[mt] = *(const bh8*)(Wb + (size_t)(v0 + mt*16 + l15)*32 + jg*8);

    // ---- GEMM2 + apply + transpose + store; two 4-deep pinned G-load groups ----
    const unsigned short* gbase = Gt + ((size_t)(n0 + wv*8))*512 + l15*32 + jg*8;
    #pragma unroll
    for (int h = 0; h < 2; ++h) {
        bh8 g0 = *(const bh8*)(gbase + (h*4+0)*512);
        bh8 g1 = *(const bh8*)(gbase + (h*4+1)*512);
        bh8 g2 = *(const bh8*)(gbase + (h*4+2)*512);
        bh8 g3 = *(const bh8*)(gbase + (h*4+3)*512);
        asm volatile("" :: "v"(g0), "v"(g1), "v"(g2), "v"(g3));
        bh8 gg[4] = {g0, g1, g2, g3};
        #pragma unroll
        for (int i = 0; i < 4; ++i) {
            int n_loc = wv*8 + h*4 + i;
            #pragma unroll
            for (int mt = 0; mt < 4; ++mt) {
                f32x4 z = {0.f, 0.f, 0.f, 0.f};
                f32x4 t = __builtin_amdgcn_mfma_f32_16x16x32_bf16(gg[i], wfrag[mt], z, 0, 0, 0);
                u16x4 vh4 = *(const u16x4*)&vhsm[n_loc*VST4 + (mt*16 + l15)*4];
                float p = t[0]*bf2f(vh4[0]) + t[1]*bf2f(vh4[1]) + t[2]*bf2f(vh4[2]) + t[3];
                float pp = __int_as_float(__builtin_amdgcn_ds_bpermute(tri, __float_as_int(p)));
                int col = vc0 + mt*48 + lane;
                if (lane < 48 && col < VC)
                    verts[(size_t)(n0 + n_loc)*VC + col] = pp;
            }
        }
    }
}

// ---------------- K_joints: JBN=64 LDS-staged MFMA GEMM (JbigT re-read halved) ----------------
__global__ __launch_bounds__(256) void k_joints(const float* __restrict__ verts,
                                                const unsigned short* __restrict__ JbigT,
                                                float* __restrict__ jpart) {
    __shared__ __attribute__((aligned(16))) unsigned short vt[JBN*128];   // 16 KB

    int tid = threadIdx.x;
    int lane = tid & 63, wv = tid >> 6;
    int l15 = lane & 15, jg = lane >> 4;
    int nt = blockIdx.x, ks = blockIdx.y;
    int n0 = nt * JBN;
    int step0 = ks * (JCH*4);          // 36 k-steps per slice

    int row[8], c4[8];
    #pragma unroll
    for (int i = 0; i < 8; ++i) {
        int idx = i*256 + tid;         // 2048 16B-units = 64 rows x 32
        row[i] = idx >> 5; c4[i] = idx & 31;
    }

    float2 rg[16];
    auto issue = [&](int ch) {         // coalesced: consecutive lanes -> consecutive 8B
        int k0f = (step0 + ch*4) * 32;
        #pragma unroll
        for (int i = 0; i < 8; ++i) {
            const float* p = verts + (size_t)(n0 + row[i])*VC + k0f + c4[i]*4;
            rg[2*i+0] = *(const float2*)(p);
            rg[2*i+1] = *(const float2*)(p+2);
        }
    };

    issue(0);
    f32x4 acc[4] = {};
    #pragma unroll 1
    for (int ch = 0; ch < JCH; ++ch) {
        __syncthreads();               // prev chunk's fragment reads done
        #pragma unroll
        for (int i = 0; i < 8; ++i) {
            u16x4 w;
            w[0] = f2bf(rg[2*i].x); w[1] = f2bf(rg[2*i].y);
            w[2] = f2bf(rg[2*i+1].x); w[3] = f2bf(rg[2*i+1].y);
            int sidx = (row[i]*128 + c4[i]*4) ^ ((row[i] & 7) << 3);
            *(u16x4*)&vt[sidx] = w;
        }
        __syncthreads();
        if (ch + 1 < JCH) issue(ch + 1);   // overlap next-stage loads with MFMAs
        #pragma unroll
        for (int kk = 0; kk < 4; ++kk) {
            bh8 b = *(const bh8*)(JbigT + ((size_t)(step0 + ch*4 + kk)*64 + wv*16 + l15)*32 + jg*8);
            #pragma unroll
            for (int m = 0; m < 4; ++m) {
                int r = m*16 + l15;
                bh8 a = *(const bh8*)&vt[(r*128 + kk*32 + jg*8) ^ ((r & 7) << 3)];
                acc[m] = __builtin_amdgcn_mfma_f32_16x16x32_bf16(a, b, acc[m], 0, 0, 0);
            }
        }
    }
    // D: col=lane&15 (kc within wave), row=(lane>>4)*4+r (n within 16-tile)
    float* jp = jpart + ((size_t)ks*NBATCH + n0)*64 + wv*16 + l15;
    #pragma unroll
    for (int m = 0; m < 4; ++m)
        #pragma unroll
        for (int r = 0; r < 4; ++r)
            jp[(size_t)(m*16 + jg*4 + r)*64] = acc[m][r];
}

// ---------------- K_jred: joints[n, i] = sum_ks jpart[ks][n][i] ----------------
__global__ __launch_bounds__(256) void k_jred(const float* __restrict__ jpart,
                                              float* __restrict__ joints) {
    int idx = blockIdx.x*256 + threadIdx.x;
    if (idx >= NBATCH*NK*3) return;
    int n = idx / (NK*3), i = idx - n*(NK*3);
    float s = 0.f;
    #pragma unroll
    for (int ks = 0; ks < JSP; ++ks)
        s += jpart[((size_t)ks*NBATCH + n)*64 + i];
    joints[idx] = s;
}

extern "C" void kernel_launch(void* const* d_in, const int* in_sizes, int n_in,
                              void* d_out, int out_size, void* d_ws, size_t ws_size,
                              hipStream_t stream) {
    const float* beta  = (const float*)d_in[0];
    const float* theta = (const float*)d_in[1];
    const float* trans = (const float*)d_in[2];
    const float* sdirs = (const float*)d_in[3];
    const float* vtmpl = (const float*)d_in[4];
    const float* jregJ = (const float*)d_in[5];
    const float* pdirs = (const float*)d_in[6];
    const float* wgts  = (const float*)d_in[7];
    const float* jregK = (const float*)d_in[8];

    float* verts  = (float*)d_out;
    float* joints = verts + (size_t)NBATCH * VC;

    char* ws = (char*)d_ws;
    float*          JB    = (float*)ws;                                      // 4096 B (zeroed)
    unsigned short* Arow  = (unsigned short*)(ws + 4096);                    // 917504 B
    unsigned short* Gt    = (unsigned short*)(ws + 4096 + 917504);           // 2097152 B
    unsigned short* Bmat  = (unsigned short*)(ws + 4096 + 917504 + 2097152); // 9289728 B
    unsigned short* JbigT = (unsigned short*)(ws + 4096 + 917504 + 2097152 + 9289728); // 2654208 B
    float*          jpart = (float*)(ws + 4096 + 917504 + 2097152 + 9289728 + 2654208); // 9437184 B
    unsigned short* Wb    = (unsigned short*)(ws + 4096 + 917504 + 2097152 + 9289728 + 2654208 + 9437184); // 440960 B

    hipMemsetAsync(JB, 0, 4096, stream);

    k_prep <<<792 + 2268 + 648 + 108, 256, 0, stream>>>(jregJ, vtmpl, sdirs, pdirs, jregK, wgts, JB, Bmat, JbigT, Wb);
    k_pern <<<NBATCH, 64, 0, stream>>>(beta, theta, trans, JB, Arow, Gt);
    dim3 g4(NBATCH/BN, (V + BV - 1)/BV);   // (32, 108), x-fastest keeps B slice L2-hot
    k_main <<<g4, 512, 0, stream>>>(Arow, Bmat, Gt, Wb, verts);
    dim3 g5(NBATCH/JBN, JSP);              // (32, 18)
    k_joints<<<g5, 256, 0, stream>>>(verts, JbigT, jpart);
    k_jred <<<(NBATCH*NK*3 + 255)/256, 256, 0, stream>>>(jpart, joints);
}

// Round 23
// 148.863 us; speedup vs baseline: 1.0231x; 1.0231x over previous
//
#include <hip/hip_runtime.h>

#define V      6890
#define NJ     24
#define NB     10
#define NP     207
#define NK     19
#define NBATCH 2048
#define KP     224      // padded K: 10 beta + 207 lrotmin + 1 const + 6 zero
#define KC     217      // constant-1 column (-> v_template)
#define VC     (V*3)    // 20670
#define VCP    20736    // padded VC
#define BN     64       // n-tile
#define BV     64       // v-tile per block
#define VST4   260      // vhsm row stride in shorts (520 B: 8B-aligned, jg-groups 8 banks apart)
#define VSEG   1723     // ceil(V/4) for V-splits (k_prep JB dots)
#define JSP    18       // joints GEMM K-split
#define JCH    9        // chunks per slice; chunk = 4 k-steps = 128 floats
#define BWSZ   1536     // per-wave per-buffer B slice, shorts (48 rows x 32)

using bh8   = __attribute__((ext_vector_type(8))) short;          // 8 x bf16
using u16x4 = __attribute__((ext_vector_type(4))) unsigned short;
using u16x8 = __attribute__((ext_vector_type(8))) unsigned short;
using f32x4 = __attribute__((ext_vector_type(4))) float;

__constant__ int PAR[NJ] = {-1,0,0,0,1,2,3,4,5,6,7,8,9,9,9,12,13,14,16,17,18,19,20,21};

__device__ __forceinline__ unsigned short f2bf(float f) {
    unsigned int u = __float_as_uint(f);
    u += 0x7FFFu + ((u >> 16) & 1u);   // RNE; no NaNs in this data
    return (unsigned short)(u >> 16);
}
__device__ __forceinline__ float bf2f(unsigned short h) {
    return __uint_as_float((unsigned int)h << 16);
}

// ---------------- K_prep: fused [JB dots | Bmat 8-wide | JbigT 8-wide | Wb bf16] ----------------
__global__ __launch_bounds__(256) void k_prep(const float* __restrict__ Jreg,
                                              const float* __restrict__ vtmpl,
                                              const float* __restrict__ sdirs,
                                              const float* __restrict__ pdirs,
                                              const float* __restrict__ jreg,
                                              const float* __restrict__ weights,
                                              float* __restrict__ JB,
                                              unsigned short* __restrict__ Bmat,
                                              unsigned short* __restrict__ JbigT,
                                              unsigned short* __restrict__ Wb) {
    int blk = blockIdx.x, tid = threadIdx.x;
    if (blk < 792) {                       // JB partial dots, 4-way V-split, atomic accumulate
        int vs = blk & 3, og = blk >> 2;
        int o = og*4 + (tid >> 6);         // o in [0,792) = 24*33
        int lane = tid & 63;
        int j = o/33, t = o%33, c = t/11, m = t%11;
        int lo = vs*VSEG + lane, hi = min(V, vs*VSEG + VSEG);
        const float* jr = Jreg + j*V;
        float s = 0.f;
        if (m == 0) { for (int v = lo; v < hi; v += 64) s += jr[v] * vtmpl[v*3 + c]; }
        else        { for (int v = lo; v < hi; v += 64) s += jr[v] * sdirs[(v*3 + c)*NB + (m-1)]; }
        #pragma unroll
        for (int d = 1; d < 64; d <<= 1) s += __shfl_xor(s, d);
        if (lane == 0) atomicAdd(&JB[(j*3 + c)*11 + m], s);
    } else if (blk < 792 + 2268) {         // Bmat: thread handles (vc, 8 consecutive k)
        int gid = (blk - 792)*256 + tid;   // [0, VCP*28)
        int vc = gid / 28, q = gid - vc*28;
        int k0 = q*8;
        unsigned short out[8];
        if (vc >= VC) {
            #pragma unroll
            for (int j = 0; j < 8; ++j) out[j] = 0;
        } else if (q >= 2 && q <= 26) {    // pure pdirs span (k in [16,215])
            const float* p = pdirs + (size_t)vc*NP + (k0 - NB);
            #pragma unroll
            for (int j = 0; j < 8; ++j) out[j] = f2bf(p[j]);
        } else {
            #pragma unroll
            for (int j = 0; j < 8; ++j) {
                int k = k0 + j;
                float val;
                if (k < NB)       val = sdirs[vc*NB + k];
                else if (k < KC)  val = pdirs[(size_t)vc*NP + (k - NB)];
                else if (k == KC) val = vtmpl[vc];
                else              val = 0.f;
                out[j] = f2bf(val);
            }
        }
        *(u16x8*)&Bmat[((size_t)(k0 >> 5)*VCP + vc)*32 + (k0 & 31)] = *(u16x8*)out;
    } else if (blk < 792 + 2268 + 648) {   // JbigT: thread handles (kc, 8 consecutive vc)
        int gid = (blk - 792 - 2268)*256 + tid;   // [0, 64*VCP/8)
        int kc = gid / (VCP/8), u = gid - kc*(VCP/8);
        int vc0 = u*8;
        unsigned short out[8];
        #pragma unroll
        for (int j = 0; j < 8; ++j) out[j] = 0;
        if (kc < NK*3) {
            #pragma unroll
            for (int j = 0; j < 8; ++j) {
                int vc = vc0 + j;
                if (vc < VC && (vc % 3) == (kc % 3))
                    out[j] = f2bf(jreg[(vc/3)*NK + (kc/3)]);
            }
        }
        *(u16x8*)&JbigT[((size_t)(vc0 >> 5)*64 + kc)*32 + (vc0 & 31)] = *(u16x8*)out;
    } else {                               // Wb[v][32] bf16: weights zero-padded to 32 cols
        int gid = (blk - 792 - 2268 - 648)*256 + tid;   // [0, V*4)
        if (gid < V*4) {
            int v = gid >> 2, q = gid & 3;
            unsigned short out[8];
            #pragma unroll
            for (int j = 0; j < 8; ++j) {
                int jj = q*8 + j;
                out[j] = (jj < NJ) ? f2bf(weights[(size_t)v*NJ + jj]) : (unsigned short)0;
            }
            *(u16x8*)&Wb[(size_t)v*32 + q*8] = *(u16x8*)out;
        }
    }
}

// ---------------- K_pern: one WAVE per n (64-thread block; barriers ~free) ----------------
__global__ __launch_bounds__(64) void k_pern(const float* __restrict__ beta,
                                             const float* __restrict__ theta,
                                             const float* __restrict__ trans,
                                             const float* __restrict__ JB,
                                             unsigned short* __restrict__ Arow,
                                             unsigned short* __restrict__ Gt) {
    int n = blockIdx.x, tid = threadIdx.x;
    __shared__ float Rsm[NJ][9];
    __shared__ float Jsm[NJ][3];
    __shared__ float Gsm[NJ][12];   // 3x4, e = a*4+b

    if (tid < NJ) {                 // lanes 0-23: rodrigues
        const float* th = theta + (n*NJ + tid)*3;
        float x = th[0], y = th[1], z = th[2];
        float nrm = sqrtf(x*x + y*y + z*z);
        float t = fmaxf(nrm, 1.1754944e-38f);
        float inv = 1.0f / t;
        float rx = x*inv, ry = y*inv, rz = z*inv;
        float c = cosf(t), s = sinf(t), oc = 1.0f - c;
        Rsm[tid][0] = c + oc*rx*rx;      Rsm[tid][1] = oc*rx*ry - s*rz;  Rsm[tid][2] = oc*rx*rz + s*ry;
        Rsm[tid][3] = oc*ry*rx + s*rz;   Rsm[tid][4] = c + oc*ry*ry;     Rsm[tid][5] = oc*ry*rz - s*rx;
        Rsm[tid][6] = oc*rz*rx - s*ry;   Rsm[tid][7] = oc*rz*ry + s*rx;  Rsm[tid][8] = c + oc*rz*rz;
    } else if (tid < 2*NJ) {        // lanes 24-47: J rows (3 dots of 11 each)
        int j = tid - NJ;
        #pragma unroll
        for (int c = 0; c < 3; ++c) {
            float s = JB[(j*3+c)*11 + 0];
            #pragma unroll
            for (int b = 0; b < NB; ++b) s += JB[(j*3+c)*11 + 1 + b] * beta[n*NB + b];
            Jsm[j][c] = s;
        }
    }
    __syncthreads();

    if (tid < 12) {
        int a = tid >> 2, b = tid & 3;
        Gsm[0][a*4+b] = (b < 3) ? Rsm[0][a*3+b] : Jsm[0][a];
    }
    __syncthreads();
    for (int i = 1; i < NJ; ++i) {
        if (tid < 12) {
            int a = tid >> 2, b = tid & 3;
            int p = PAR[i];
            float acc = (b == 3) ? Gsm[p][a*4+3] : 0.0f;
            #pragma unroll
            for (int k = 0; k < 3; ++k) {
                float aval = (b < 3) ? Rsm[i][k*3+b] : (Jsm[i][k] - Jsm[p][k]);
                acc += Gsm[p][a*4+k] * aval;
            }
            Gsm[i][a*4+b] = acc;
        }
        __syncthreads();
    }
    if (tid < NJ) {   // t' = t - R.J + trans (trans folds: sum_j w = 1)
        int j = tid;
        #pragma unroll
        for (int a = 0; a < 3; ++a) {
            float t3 = Gsm[j][a*4+3]
                     - (Gsm[j][a*4+0]*Jsm[j][0] + Gsm[j][a*4+1]*Jsm[j][1] + Gsm[j][a*4+2]*Jsm[j][2])
                     + trans[n*3 + a];
            Gsm[j][a*4+3] = t3;
        }
    }
    __syncthreads();
    // Gt[n][e=0..15][j=0..31] bf16 zero-padded
    unsigned short* gt = Gt + n*512;
    for (int idx = tid; idx < 512; idx += 64) {
        int e = idx >> 5, j = idx & 31;
        float val = (e < 12 && j < NJ) ? Gsm[j][e] : 0.0f;
        gt[idx] = f2bf(val);
    }
    // A-row, K-tiled layout [k/32][n][32]
    for (int k = tid; k < KP; k += 64) {
        float val;
        if (k < NB) val = beta[n*NB + k];
        else if (k < KC) {
            int p = k - NB; int jj = p/9 + 1; int rr = p%9;
            val = Rsm[jj][rr] - ((rr==0 || rr==4 || rr==8) ? 1.0f : 0.0f);
        } else if (k == KC) val = 1.0f;
        else val = 0.0f;
        Arow[((size_t)(k >> 5)*NBATCH + n)*32 + (k & 31)] = f2bf(val);
    }
}

// ---------------- K_main: R18/R20/R21 structure; GEMM2 stores direct (bpermute removed) ----------------
// R23: the ds_bpermute transpose was vestigial (added in R4 for NT stores, which
// were dropped in R8). Direct per-lane stores at col=(v')*3+jg touch the same
// 192B-contiguous footprint (coalescer merges by cache line, not lane order),
// removing 32 LDS-path ops + lgkm waits per wave from the GEMM2 chain.
__global__ __launch_bounds__(512) void k_main(const unsigned short* __restrict__ Arow,
                                              const unsigned short* __restrict__ Bmat,
                                              const unsigned short* __restrict__ Gt,
                                              const unsigned short* __restrict__ Wb,
                                              float* __restrict__ verts) {
    __shared__ __attribute__((aligned(16))) char smem[49152];
    unsigned short* Bw   = (unsigned short*)smem;   // [8 waves][2 bufs][BWSZ]
    unsigned short* vhsm = (unsigned short*)smem;   // overlaid [BN*VST4] (33280 B)

    int tid = threadIdx.x;
    int wv = tid >> 6, lane = tid & 63;
    int l15 = lane & 15, jg = lane >> 4;
    int wn = wv >> 2, wc = wv & 3;             // n-half (0/1), vc-quarter (0..3)
    int nb = blockIdx.x, vb = blockIdx.y;      // x-fastest: 32 consecutive blocks share B slice
    int n0 = nb * BN, v0 = vb * BV, vc0 = v0 * 3;

    // per-lane spill column mapping (vc -> padded-4 col)
    int c4[3];
    #pragma unroll
    for (int ct = 0; ct < 3; ++ct) {
        int vcw = wc*48 + ct*16 + l15;          // [0,192)
        c4[ct] = (vcw/3)*4 + vcw%3;
    }

    unsigned short* bw0 = &Bw[wv*2*BWSZ];
    unsigned short* bw1 = bw0 + BWSZ;
    const unsigned short* bsrc0 = Bmat + ((size_t)(vc0 + wc*48))*32;
    auto stageB = [&](unsigned short* dst, int ks) {   // 3 x 1KB async, zero VGPR payload
        const unsigned short* s = bsrc0 + (size_t)ks*VCP*32;
        #pragma unroll
        for (int i = 0; i < 3; ++i) {
            __builtin_amdgcn_global_load_lds(
                (const __attribute__((address_space(1))) void*)(s + i*512 + (size_t)lane*8),
                (__attribute__((address_space(3))) void*)(dst + i*512),
                16, 0, 0);
        }
    };

    const unsigned short* abase = Arow + ((size_t)(n0 + wn*32) + l15)*32 + jg*8;

    // ---- prologue: issue groups {S(0),A(0)} and {S(1),A(1)}, order pinned ----
    stageB(bw0, 0);
    bh8 aA0 = *(const bh8*)(abase);
    bh8 aA1 = *(const bh8*)(abase + 16*32);
    __builtin_amdgcn_sched_barrier(0);
    stageB(bw1, 1);
    bh8 aB0 = *(const bh8*)(abase + (size_t)NBATCH*32);
    bh8 aB1 = *(const bh8*)(abase + (size_t)NBATCH*32 + 16*32);
    __builtin_amdgcn_sched_barrier(0);

    // ---- GEMM1: counted-vmcnt depth-2 pipeline, NO block barriers ----
    f32x4 acc[2][3] = {};
    #pragma unroll
    for (int ks = 0; ks < 7; ++ks) {
        // queue (oldest first): group(ks)=5, group(ks+1)=5  -> wait group(ks) only
        if (ks < 6) asm volatile("s_waitcnt vmcnt(5)" ::: "memory");
        else        asm volatile("s_waitcnt vmcnt(0)" ::: "memory");
        __builtin_amdgcn_sched_barrier(0);
        unsigned short* bcur = (ks & 1) ? bw1 : bw0;
        bh8 b0 = *(const bh8*)(bcur + ( 0 + l15)*32 + jg*8);
        bh8 b1 = *(const bh8*)(bcur + (16 + l15)*32 + jg*8);
        bh8 b2 = *(const bh8*)(bcur + (32 + l15)*32 + jg*8);
        asm volatile("s_waitcnt lgkmcnt(0)" ::: "memory");   // b in regs -> bcur reusable
        __builtin_amdgcn_sched_barrier(0);
        bh8 a0 = (ks & 1) ? aB0 : aA0;
        bh8 a1 = (ks & 1) ? aB1 : aA1;
        if (ks + 2 <= 6) {        // issue group(ks+2) into bcur (now free)
            stageB(bcur, ks + 2);
            if (ks & 1) {
                aB0 = *(const bh8*)(abase + (size_t)(ks+2)*NBATCH*32);
                aB1 = *(const bh8*)(abase + (size_t)(ks+2)*NBATCH*32 + 16*32);
            } else {
                aA0 = *(const bh8*)(abase + (size_t)(ks+2)*NBATCH*32);
                aA1 = *(const bh8*)(abase + (size_t)(ks+2)*NBATCH*32 + 16*32);
            }
            __builtin_amdgcn_sched_barrier(0);
        }
        __builtin_amdgcn_s_setprio(1);
        acc[0][0] = __builtin_amdgcn_mfma_f32_16x16x32_bf16(a0, b0, acc[0][0], 0, 0, 0);
        acc[0][1] = __builtin_amdgcn_mfma_f32_16x16x32_bf16(a0, b1, acc[0][1], 0, 0, 0);
        acc[0][2] = __builtin_amdgcn_mfma_f32_16x16x32_bf16(a0, b2, acc[0][2], 0, 0, 0);
        acc[1][0] = __builtin_amdgcn_mfma_f32_16x16x32_bf16(a1, b0, acc[1][0], 0, 0, 0);
        acc[1][1] = __builtin_amdgcn_mfma_f32_16x16x32_bf16(a1, b1, acc[1][1], 0, 0, 0);
        acc[1][2] = __builtin_amdgcn_mfma_f32_16x16x32_bf16(a1, b2, acc[1][2], 0, 0, 0);
        __builtin_amdgcn_s_setprio(0);
    }

    __syncthreads();   // all waves done with Bw -> region becomes vhsm

    // spill (bf16, padded-4): row = wn*32 + mt*16 + jg*4 + r, col = c4[ct]
    #pragma unroll
    for (int mt = 0; mt < 2; ++mt)
        #pragma unroll
        for (int ct = 0; ct < 3; ++ct)
            #pragma unroll
            for (int r = 0; r < 4; ++r)
                vhsm[(wn*32 + mt*16 + jg*4 + r)*VST4 + c4[ct]] = f2bf(acc[mt][ct][r]);
    __syncthreads();

    // W fragments: single 16B loads from pre-converted Wb (jg=3 rows read zeros)
    bh8 wfrag[4];
    #pragma unroll
    for (int mt = 0; mt < 4; ++mt)
        wfrag[mt] = *(const bh8*)(Wb + (size_t)(v0 + mt*16 + l15)*32 + jg*8);

    // ---- GEMM2 + apply + direct store; two 4-deep pinned G-load groups ----
    const unsigned short* gbase = Gt + ((size_t)(n0 + wv*8))*512 + l15*32 + jg*8;
    #pragma unroll
    for (int h = 0; h < 2; ++h) {
        bh8 g0 = *(const bh8*)(gbase + (h*4+0)*512);
        bh8 g1 = *(const bh8*)(gbase + (h*4+1)*512);
        bh8 g2 = *(const bh8*)(gbase + (h*4+2)*512);
        bh8 g3 = *(const bh8*)(gbase + (h*4+3)*512);
        asm volatile("" :: "v"(g0), "v"(g1), "v"(g2), "v"(g3));
        bh8 gg[4] = {g0, g1, g2, g3};
        #pragma unroll
        for (int i = 0; i < 4; ++i) {
            int n_loc = wv*8 + h*4 + i;
            #pragma unroll
            for (int mt = 0; mt < 4; ++mt) {
                f32x4 z = {0.f, 0.f, 0.f, 0.f};
                f32x4 t = __builtin_amdgcn_mfma_f32_16x16x32_bf16(gg[i], wfrag[mt], z, 0, 0, 0);
                u16x4 vh4 = *(const u16x4*)&vhsm[n_loc*VST4 + (mt*16 + l15)*4];
                float p = t[0]*bf2f(vh4[0]) + t[1]*bf2f(vh4[1]) + t[2]*bf2f(vh4[2]) + t[3];
                int col = vc0 + (mt*16 + l15)*3 + jg;   // lane holds verts[n][v'][a=jg]
                if (jg < 3 && col < VC)
                    verts[(size_t)(n0 + n_loc)*VC + col] = p;
            }
        }
    }
}

// ---------------- K_joints: LDS-staged MFMA GEMM  jpart[ks][n][kc] += verts x JbigT ----------------
__global__ __launch_bounds__(256) void k_joints(const float* __restrict__ verts,
                                                const unsigned short* __restrict__ JbigT,
                                                float* __restrict__ jpart) {
    __shared__ __attribute__((aligned(16))) unsigned short vt[32*128];   // 8 KB

    int tid = threadIdx.x;
    int lane = tid & 63, wv = tid >> 6;
    int l15 = lane & 15, jg = lane >> 4;
    int nt = blockIdx.x, ks = blockIdx.y;
    int n0 = nt * 32;
    int step0 = ks * (JCH*4);          // 36 k-steps per slice

    int row[4], c4[4];
    #pragma unroll
    for (int i = 0; i < 4; ++i) {
        int idx = i*256 + tid;         // 1024 16B-units = 32 rows x 32
        row[i] = idx >> 5; c4[i] = idx & 31;
    }

    float2 rg[8];
    auto issue = [&](int ch) {         // coalesced: consecutive lanes -> consecutive 8B
        int k0f = (step0 + ch*4) * 32;
        #pragma unroll
        for (int i = 0; i < 4; ++i) {
            const float* p = verts + (size_t)(n0 + row[i])*VC + k0f + c4[i]*4;
            rg[2*i+0] = *(const float2*)(p);
            rg[2*i+1] = *(const float2*)(p+2);
        }
    };

    issue(0);
    f32x4 acc[2] = {};
    #pragma unroll 1
    for (int ch = 0; ch < JCH; ++ch) {
        __syncthreads();               // prev chunk's fragment reads done
        #pragma unroll
        for (int i = 0; i < 4; ++i) {
            u16x4 w;
            w[0] = f2bf(rg[2*i].x); w[1] = f2bf(rg[2*i].y);
            w[2] = f2bf(rg[2*i+1].x); w[3] = f2bf(rg[2*i+1].y);
            int sidx = (row[i]*128 + c4[i]*4) ^ ((row[i] & 7) << 3);
            *(u16x4*)&vt[sidx] = w;
        }
        __syncthreads();
        if (ch + 1 < JCH) issue(ch + 1);   // overlap next-stage loads with MFMAs
        #pragma unroll
        for (int kk = 0; kk < 4; ++kk) {
            int r0 = l15, r1 = 16 + l15;
            bh8 a0 = *(const bh8*)&vt[(r0*128 + kk*32 + jg*8) ^ ((r0 & 7) << 3)];
            bh8 a1 = *(const bh8*)&vt[(r1*128 + kk*32 + jg*8) ^ ((r1 & 7) << 3)];
            bh8 b  = *(const bh8*)(JbigT + ((size_t)(step0 + ch*4 + kk)*64 + wv*16 + l15)*32 + jg*8);
            acc[0] = __builtin_amdgcn_mfma_f32_16x16x32_bf16(a0, b, acc[0], 0, 0, 0);
            acc[1] = __builtin_amdgcn_mfma_f32_16x16x32_bf16(a1, b, acc[1], 0, 0, 0);
        }
    }
    // D: col=lane&15 (kc within wave), row=(lane>>4)*4+r (n within 16-tile)
    float* jp = jpart + ((size_t)ks*NBATCH + n0)*64 + wv*16 + l15;
    #pragma unroll
    for (int mt = 0; mt < 2; ++mt)
        #pragma unroll
        for (int r = 0; r < 4; ++r)
            jp[(size_t)(mt*16 + jg*4 + r)*64] = acc[mt][r];
}

// ---------------- K_jred: joints[n, i] = sum_ks jpart[ks][n][i] ----------------
__global__ __launch_bounds__(256) void k_jred(const float* __restrict__ jpart,
                                              float* __restrict__ joints) {
    int idx = blockIdx.x*256 + threadIdx.x;
    if (idx >= NBATCH*NK*3) return;
    int n = idx / (NK*3), i = idx - n*(NK*3);
    float s = 0.f;
    #pragma unroll
    for (int ks = 0; ks < JSP; ++ks)
        s += jpart[((size_t)ks*NBATCH + n)*64 + i];
    joints[idx] = s;
}

extern "C" void kernel_launch(void* const* d_in, const int* in_sizes, int n_in,
                              void* d_out, int out_size, void* d_ws, size_t ws_size,
                              hipStream_t stream) {
    const float* beta  = (const float*)d_in[0];
    const float* theta = (const float*)d_in[1];
    const float* trans = (const float*)d_in[2];
    const float* sdirs = (const float*)d_in[3];
    const float* vtmpl = (const float*)d_in[4];
    const float* jregJ = (const float*)d_in[5];
    const float* pdirs = (const float*)d_in[6];
    const float* wgts  = (const float*)d_in[7];
    const float* jregK = (const float*)d_in[8];

    float* verts  = (float*)d_out;
    float* joints = verts + (size_t)NBATCH * VC;

    char* ws = (char*)d_ws;
    float*          JB    = (float*)ws;                                      // 4096 B (zeroed)
    unsigned short* Arow  = (unsigned short*)(ws + 4096);                    // 917504 B
    unsigned short* Gt    = (unsigned short*)(ws + 4096 + 917504);           // 2097152 B
    unsigned short* Bmat  = (unsigned short*)(ws + 4096 + 917504 + 2097152); // 9289728 B
    unsigned short* JbigT = (unsigned short*)(ws + 4096 + 917504 + 2097152 + 9289728); // 2654208 B
    float*          jpart = (float*)(ws + 4096 + 917504 + 2097152 + 9289728 + 2654208); // 9437184 B
    unsigned short* Wb    = (unsigned short*)(ws + 4096 + 917504 + 2097152 + 9289728 + 2654208 + 9437184); // 440960 B

    hipMemsetAsync(JB, 0, 4096, stream);

    k_prep <<<792 + 2268 + 648 + 108, 256, 0, stream>>>(jregJ, vtmpl, sdirs, pdirs, jregK, wgts, JB, Bmat, JbigT, Wb);
    k_pern <<<NBATCH, 64, 0, stream>>>(beta, theta, trans, JB, Arow, Gt);
    dim3 g4(NBATCH/BN, (V + BV - 1)/BV);   // (32, 108), x-fastest keeps B slice L2-hot
    k_main <<<g4, 512, 0, stream>>>(Arow, Bmat, Gt, Wb, verts);
    dim3 g5(NBATCH/32, JSP);               // (64, 18)
    k_joints<<<g5, 256, 0, stream>>>(verts, JbigT, jpart);
    k_jred <<<(NBATCH*NK*3 + 255)/256, 256, 0, stream>>>(jpart, joints);
}